// Round 16
// baseline (43.322 us; speedup 1.0000x reference)
//
#include <hip/hip_runtime.h>

typedef __attribute__((ext_vector_type(8)))  __bf16    bf16x8;
typedef __attribute__((ext_vector_type(4)))  __bf16    bf16x4;
typedef __attribute__((ext_vector_type(16))) float     f32x16;
typedef __attribute__((ext_vector_type(4)))  _Float16  f16x4;
typedef __attribute__((ext_vector_type(2)))  __fp16    h16x2;
typedef __attribute__((ext_vector_type(8)))  __fp16    h16x8;

constexpr int NG  = 2048;
constexpr int NN  = 64;
constexpr int DD  = 128;
constexpr int KK  = 128;
constexpr int OUTD = 10;

// upper-triangular 32x32 tile list: t -> (ti, tj), ti <= tj
__device__ __host__ inline void tileOf(int t, int& ti, int& tj) {
    if (t < 4)      { ti = 0; tj = t;     }
    else if (t < 7) { ti = 1; tj = t - 3; }
    else if (t < 9) { ti = 2; tj = t - 5; }
    else            { ti = 3; tj = 3;     }
}

// XtL: 64-elem rows -> XOR elem bits 3-5 with row&7
__device__ inline int xtIdx(int r, int c) { return r * 64  + (c ^ ((r & 7) << 3)); }
// GL: 128-elem rows -> XOR elem bits 3-6 with row&15
__device__ inline int gIdx (int r, int c) { return r * 128 + (c ^ ((r & 15) << 3)); }

#if __has_builtin(__builtin_amdgcn_fdot2)
__device__ __forceinline__ float dot2f(h16x2 a, h16x2 b, float c) {
    return __builtin_amdgcn_fdot2(a, b, c, false);
}
#else
__device__ __forceinline__ float dot2f(h16x2 a, h16x2 b, float c) {
    return c + (float)a[0] * (float)b[0] + (float)a[1] * (float)b[1];
}
#endif

// ---------------------------------------------------------------------------
// Fused setup kernel (R15-proven): one block per (o, tile). Computes the two
// 32x32 A-tiles for S tile t directly from Wa/W1 (ascending-k f32 FMA chain),
// packs Sp (f16, D-fragment order, diag zeros baked). ti==0 blocks emit cg.
//   Sp[((o*10+t)*64 + lane)*16 + r] = S[ti*32 + (r&3)+8*(r>>2)+4*(lane>>5), tj*32 + (lane&31)]
// ---------------------------------------------------------------------------
__global__ __launch_bounds__(256)
void fused_sp_kernel(const float* __restrict__ Wa,
                     const float* __restrict__ b_att,
                     const float* __restrict__ W1,
                     _Float16* __restrict__ Sp,
                     float* __restrict__ cgout)
{
    const int blk = blockIdx.x;
    const int o = blk / 10, t = blk - o * 10;
    int ti, tj; tileOf(t, ti, tj);
    const int Fi = ti * 32, Ej = tj * 32;
    const float* __restrict__ W1o = W1 + (size_t)o * (KK * DD);

    __shared__ float WaF[KK][32];   // Wa[k][Fi+j]
    __shared__ float WaE[KK][32];   // Wa[k][Ej+j]
    __shared__ float W1F[KK][32];   // W1o[k][Fi+j]
    __shared__ float W1E[KK][32];   // W1o[k][Ej+j]
    __shared__ float AFE[32][33];   // A[Fi+f][Ej+e]  (padded)
    __shared__ float AEF[32][33];   // A[Ej+e][Fi+f]  (padded)
    __shared__ float bsh[KK];

    const int tid = threadIdx.x;

    // ---- stage panels (coalesced 128B rows) ----
    for (int r0 = 0; r0 < KK; r0 += 8) {
        const int r = r0 + (tid >> 5), cc = tid & 31;
        WaF[r][cc] = Wa[r * DD + Fi + cc];
        WaE[r][cc] = Wa[r * DD + Ej + cc];
        W1F[r][cc] = W1o[r * DD + Fi + cc];
        W1E[r][cc] = W1o[r * DD + Ej + cc];
    }
    if (tid < KK) bsh[tid] = b_att[tid];
    __syncthreads();

    // ---- compute A tiles: thread -> row (tid>>3), 4 cols ((tid&7)*4) ----
    {
        const int rloc = tid >> 3;          // 0..31
        const int q    = (tid & 7) * 4;     // 0,4,..,28
        float a0 = 0.f, a1 = 0.f, a2 = 0.f, a3 = 0.f;
        float b0 = 0.f, b1 = 0.f, b2 = 0.f, b3 = 0.f;
        for (int k = 0; k < KK; ++k) {
            const float av = WaF[k][rloc];
            const float4 wv = *(const float4*)&W1E[k][q];
            a0 += av * wv.x; a1 += av * wv.y; a2 += av * wv.z; a3 += av * wv.w;
            const float bv = WaE[k][rloc];
            const float4 vv = *(const float4*)&W1F[k][q];
            b0 += bv * vv.x; b1 += bv * vv.y; b2 += bv * vv.z; b3 += bv * vv.w;
        }
        AFE[rloc][q] = a0; AFE[rloc][q + 1] = a1; AFE[rloc][q + 2] = a2; AFE[rloc][q + 3] = a3;
        AEF[rloc][q] = b0; AEF[rloc][q + 1] = b1; AEF[rloc][q + 2] = b2; AEF[rloc][q + 3] = b3;
    }
    __syncthreads();

    // ---- pack S tile (proven indexing) ----
    {
        const int l  = tid & 63;
        const int rq = tid >> 6;            // 0..3
        const int eg = l & 31;              // e local
        const int e  = Ej + eg;
        f16x4 p;
#pragma unroll
        for (int j = 0; j < 4; ++j) {
            const int fl = j + 8 * rq + 4 * (l >> 5);
            const int f  = Fi + fl;
            float v;
            if (f < e)       v = AFE[fl][eg] + AEF[eg][fl];
            else if (f == e) v = AFE[fl][eg];
            else             v = 0.f;
            p[j] = (_Float16)v;
        }
        *(f16x4*)&Sp[(size_t)((o * 10 + t) * 64 + l) * 16 + rq * 4] = p;
    }

    // ---- cg (ti==0 blocks cover all e via tj=0..3) ----
    if (ti == 0 && tid < 32) {
        float s = 0.f;
        for (int k = 0; k < KK; ++k) s += bsh[k] * W1E[k][tid];
        cgout[o * DD + Ej + tid] = s;
    }
}

// ---------------------------------------------------------------------------
// Per-graph phases 0-3 (R7-proven). Produces colsum sOut[128] (waves 2,3),
// hacc0 (tile w), and accumulates extra tiles 8,9 into haccX on waves
// extraBase, extraBase+1 (haccX shared between graphs on disjoint wave pairs).
// ---------------------------------------------------------------------------
__device__ __forceinline__ void process_graph(
    const float* __restrict__ xg,
    __bf16* __restrict__ XtL, __bf16* __restrict__ GL,
    float (*__restrict__ sp)[DD], float* __restrict__ sOut,
    int tid, int w, int l, int l31, int l5, int extraBase,
    f32x16& hacc0, f32x16& haccX)
{
    // ---- phase 0: load X column-wise, store X^T as bf16 (RNE) ----
    {
        const int f = tid & 127, half = tid >> 7;
#pragma unroll
        for (int ch = 0; ch < 2; ++ch) {
            float v[8];
#pragma unroll
            for (int i = 0; i < 8; ++i) v[i] = xg[(half * 16 + ch * 8 + i) * DD + f];
            bf16x8 p;
#pragma unroll
            for (int i = 0; i < 8; ++i) p[i] = (__bf16)v[i];
            *(bf16x8*)&XtL[xtIdx(f, half * 16 + ch * 8)] = p;
        }
    }
    __syncthreads();

    // ---- phase 1: gram tiles. wave w: ti = w&3, tj = {2*(w>>2), +1} ----
    const int ti  = w & 3;
    const int tj0 = (w >> 2) * 2;
    f32x16 acc0, acc1;
#pragma unroll
    for (int i = 0; i < 16; ++i) { acc0[i] = 0.f; acc1[i] = 0.f; }
    {
        const int arow  = ti  * 32 + l31;
        const int brow0 = tj0 * 32 + l31;
#pragma unroll
        for (int ks = 0; ks < 4; ++ks) {
            const int kc = ks * 16 + l5 * 8;
            bf16x8 a  = *(const bf16x8*)&XtL[xtIdx(arow, kc)];
            bf16x8 b0 = *(const bf16x8*)&XtL[xtIdx(brow0, kc)];
            bf16x8 b1 = *(const bf16x8*)&XtL[xtIdx(brow0 + 32, kc)];
            acc0 = __builtin_amdgcn_mfma_f32_32x32x16_bf16(a, b0, acc0, 0, 0, 0);
            acc1 = __builtin_amdgcn_mfma_f32_32x32x16_bf16(a, b1, acc1, 0, 0, 0);
        }
    }
    __syncthreads();   // XtL reads done; GL may overwrite

    // ---- phase 2: quantize, store G transposed (symmetric) + column partials ----
    {
        float sum0 = 0.f, sum1 = 0.f;
#pragma unroll
        for (int tt = 0; tt < 2; ++tt) {
            const int e = (tj0 + tt) * 32 + l31;       // row of G (transposed write)
#pragma unroll
            for (int g2 = 0; g2 < 4; ++g2) {
                bf16x4 p;
#pragma unroll
                for (int j = 0; j < 4; ++j) {
                    const float av = tt ? acc1[g2 * 4 + j] : acc0[g2 * 4 + j];
                    const float q = rintf(av * 100.f) * 0.01f;
                    p[j] = (__bf16)q;
                    if (tt) sum1 += q; else sum0 += q;
                }
                const int fbase = ti * 32 + g2 * 8 + l5 * 4;
                *(bf16x4*)&GL[gIdx(e, fbase)] = p;
            }
        }
        sp[ti * 2 + l5][tj0 * 32 + l31]       = sum0;
        sp[ti * 2 + l5][(tj0 + 1) * 32 + l31] = sum1;
    }
    __syncthreads();   // G + sp complete

    // ---- phase 2.5 (waves 2,3): gather colsum ----
    if (w == 2 || w == 3) {
        const int e = (w - 2) * 64 + l;
        float s = 0.f;
#pragma unroll
        for (int i = 0; i < 8; ++i) s += sp[i][e];
        sOut[e] = s;
    }

    // ---- phase 3: H = G*G upper-tri tiles (extras 8,9 on extraBase,+1) ----
#pragma unroll
    for (int i = 0; i < 16; ++i) hacc0[i] = 0.f;
    {
        int hti, htj; tileOf(w, hti, htj);
        const int ra = hti * 32 + l31, rb = htj * 32 + l31;
#pragma unroll
        for (int ks = 0; ks < 8; ++ks) {
            const int kc = ks * 16 + l5 * 8;
            bf16x8 a = *(const bf16x8*)&GL[gIdx(ra, kc)];
            bf16x8 b = *(const bf16x8*)&GL[gIdx(rb, kc)];
            hacc0 = __builtin_amdgcn_mfma_f32_32x32x16_bf16(a, b, hacc0, 0, 0, 0);
        }
    }
    if (w == extraBase || w == extraBase + 1) {
        int ti1, tj1; tileOf(8 + (w - extraBase), ti1, tj1);
        const int ra = ti1 * 32 + l31, rb = tj1 * 32 + l31;
#pragma unroll
        for (int ks = 0; ks < 8; ++ks) {
            const int kc = ks * 16 + l5 * 8;
            bf16x8 a = *(const bf16x8*)&GL[gIdx(ra, kc)];
            bf16x8 b = *(const bf16x8*)&GL[gIdx(rb, kc)];
            haccX = __builtin_amdgcn_mfma_f32_32x32x16_bf16(a, b, haccX, 0, 0, 0);
        }
    }
    __syncthreads();   // GL reads done (region reusable); sOut visible
}

// ---------------------------------------------------------------------------
// Kernel 2: one block per TWO graphs, 512 threads = 8 waves (R14 structure).
// ONLY change vs R15: __launch_bounds__(512, 2) relaxes the compiler's
// 64-VGPR self-cap so ph4's 40 L2 loads can pipeline deeper (R10 showed
// this picks ~76 VGPR; 76+48 AGPR = 124 <= 128 keeps 4 waves/SIMD).
// ---------------------------------------------------------------------------
__global__ __launch_bounds__(512, 2)
void graph_kernel(const float* __restrict__ x,
                  const _Float16* __restrict__ Sp,
                  const float* __restrict__ cg,
                  const float* __restrict__ bias1,
                  float* __restrict__ out)
{
    __shared__ __align__(16) char ldsraw[20 * 512 * 4];   // 40 KB
    __shared__ float sp[8][DD];                           // 4 KB
    __shared__ float sA[DD], sB[DD];

    __bf16* const XtL = (__bf16*)ldsraw;
    __bf16* const GL  = (__bf16*)ldsraw;
    float*  const PP  = (float*)ldsraw;

    const int g0  = blockIdx.x * 2;
    const int g1  = g0 + 1;
    const int tid = threadIdx.x;
    const int w   = tid >> 6;
    const int l   = tid & 63;
    const int l31 = l & 31;
    const int l5  = l >> 5;

    f32x16 hA0, hB0, hX1;
#pragma unroll
    for (int i = 0; i < 16; ++i) hX1[i] = 0.f;

    process_graph(x + (size_t)g0 * NN * DD, XtL, GL, sp, sA,
                  tid, w, l, l31, l5, /*extraBase=*/6, hA0, hX1);
    process_graph(x + (size_t)g1 * NN * DD, XtL, GL, sp, sB,
                  tid, w, l, l31, l5, /*extraBase=*/4, hB0, hX1);

    // ---- convert H accumulators to packed half2 (AGPRs die here) ----
    h16x2 hA[8], hB[8], hX[8];
#pragma unroll
    for (int i = 0; i < 8; ++i) {
        hA[i] = __builtin_amdgcn_cvt_pkrtz(hA0[2 * i], hA0[2 * i + 1]);
        hB[i] = __builtin_amdgcn_cvt_pkrtz(hB0[2 * i], hB0[2 * i + 1]);
        hX[i] = __builtin_amdgcn_cvt_pkrtz(hX1[2 * i], hX1[2 * i + 1]);
    }

    // ---- phase 4: contraction with Sp (f16, fragment order; zeros baked) ----
#pragma unroll
    for (int o = 0; o < OUTD; ++o) {
        const _Float16* __restrict__ spp = Sp + (size_t)((o * 10 + w) * 64 + l) * 16;
        const h16x8 s0 = *(const h16x8*)&spp[0];
        const h16x8 s1 = *(const h16x8*)&spp[8];
        float tA = 0.f, tB = 0.f;
#pragma unroll
        for (int i = 0; i < 4; ++i) {
            const h16x2 p = { s0[2 * i], s0[2 * i + 1] };
            tA = dot2f(p, hA[i], tA);
            tB = dot2f(p, hB[i], tB);
        }
#pragma unroll
        for (int i = 0; i < 4; ++i) {
            const h16x2 p = { s1[2 * i], s1[2 * i + 1] };
            tA = dot2f(p, hA[4 + i], tA);
            tB = dot2f(p, hB[4 + i], tB);
        }
        if (w >= 4) {   // extra tiles: t2 = 8+(w&1); A on waves 6,7 / B on 4,5
            const _Float16* __restrict__ sp2 =
                Sp + (size_t)((o * 10 + 8 + (w & 1)) * 64 + l) * 16;
            const h16x8 e0 = *(const h16x8*)&sp2[0];
            const h16x8 e1 = *(const h16x8*)&sp2[8];
            float tx = 0.f;
#pragma unroll
            for (int i = 0; i < 4; ++i) {
                const h16x2 p = { e0[2 * i], e0[2 * i + 1] };
                tx = dot2f(p, hX[i], tx);
            }
#pragma unroll
            for (int i = 0; i < 4; ++i) {
                const h16x2 p = { e1[2 * i], e1[2 * i + 1] };
                tx = dot2f(p, hX[4 + i], tx);
            }
            if (w >= 6) tA += tx; else tB += tx;
        }
        if (w == 0) {
            tA += cg[o * DD + l] * sA[l] + cg[o * DD + 64 + l] * sA[64 + l];
            tB += cg[o * DD + l] * sB[l] + cg[o * DD + 64 + l] * sB[64 + l];
        }
        PP[o * 512 + tid]        = tA;
        PP[(10 + o) * 512 + tid] = tB;
    }
    __syncthreads();

    // ---- phase 5: 20 reduce instances over 8 waves ----
    for (int p = w; p < 2 * OUTD; p += 8) {
        const float4 q0 = *(const float4*)&PP[p * 512 + l * 8];
        const float4 q1 = *(const float4*)&PP[p * 512 + l * 8 + 4];
        float v = (q0.x + q0.y) + (q0.z + q0.w) + (q1.x + q1.y) + (q1.z + q1.w);
        v += __shfl_down(v, 32, 64);
        v += __shfl_down(v, 16, 64);
        v += __shfl_down(v, 8, 64);
        v += __shfl_down(v, 4, 64);
        v += __shfl_down(v, 2, 64);
        v += __shfl_down(v, 1, 64);
        if (l == 0) {
            const int gg = (p < OUTD) ? g0 : g1;
            const int oo = (p < OUTD) ? p : p - OUTD;
            out[(size_t)gg * OUTD + oo] = v + bias1[oo];
        }
    }
}

// ---------------------------------------------------------------------------
extern "C" void kernel_launch(void* const* d_in, const int* in_sizes, int n_in,
                              void* d_out, int out_size, void* d_ws, size_t ws_size,
                              hipStream_t stream)
{
    const float* x     = (const float*)d_in[0];
    const float* Wa    = (const float*)d_in[1];
    const float* b_att = (const float*)d_in[2];
    const float* W1    = (const float*)d_in[3];
    const float* bias1 = (const float*)d_in[4];
    float* out = (float*)d_out;

    float*    cg = (float*)d_ws;                     // 1280 f32 (5 KB)
    _Float16* Sp = (_Float16*)(cg + OUTD * DD);      // 102400 f16 (200 KB)

    fused_sp_kernel<<<100, 256, 0, stream>>>(Wa, b_att, W1, Sp, cg);
    graph_kernel<<<NG / 2, 512, 0, stream>>>(x, Sp, cg, bias1, out);
}

// Round 17
// 42.751 us; speedup vs baseline: 1.0134x; 1.0134x over previous
//
#include <hip/hip_runtime.h>

typedef __attribute__((ext_vector_type(8)))  __bf16    bf16x8;
typedef __attribute__((ext_vector_type(4)))  __bf16    bf16x4;
typedef __attribute__((ext_vector_type(16))) float     f32x16;
typedef __attribute__((ext_vector_type(4)))  _Float16  f16x4;
typedef __attribute__((ext_vector_type(2)))  __fp16    h16x2;
typedef __attribute__((ext_vector_type(8)))  __fp16    h16x8;

constexpr int NG  = 2048;
constexpr int NN  = 64;
constexpr int DD  = 128;
constexpr int KK  = 128;
constexpr int OUTD = 10;

// upper-triangular 32x32 tile list: t -> (ti, tj), ti <= tj
__device__ __host__ inline void tileOf(int t, int& ti, int& tj) {
    if (t < 4)      { ti = 0; tj = t;     }
    else if (t < 7) { ti = 1; tj = t - 3; }
    else if (t < 9) { ti = 2; tj = t - 5; }
    else            { ti = 3; tj = 3;     }
}

// XtL: 64-elem rows -> XOR elem bits 3-5 with row&7
__device__ inline int xtIdx(int r, int c) { return r * 64  + (c ^ ((r & 7) << 3)); }
// GL: 128-elem rows -> XOR elem bits 3-6 with row&15
__device__ inline int gIdx (int r, int c) { return r * 128 + (c ^ ((r & 15) << 3)); }

#if __has_builtin(__builtin_amdgcn_fdot2)
__device__ __forceinline__ float dot2f(h16x2 a, h16x2 b, float c) {
    return __builtin_amdgcn_fdot2(a, b, c, false);
}
#else
__device__ __forceinline__ float dot2f(h16x2 a, h16x2 b, float c) {
    return c + (float)a[0] * (float)b[0] + (float)a[1] * (float)b[1];
}
#endif

// ---------------------------------------------------------------------------
// Fused setup kernel (R15-proven): one block per (o, tile).
//   Sp[((o*10+t)*64 + lane)*16 + r] = S[ti*32 + (r&3)+8*(r>>2)+4*(lane>>5), tj*32 + (lane&31)]
// ---------------------------------------------------------------------------
__global__ __launch_bounds__(256)
void fused_sp_kernel(const float* __restrict__ Wa,
                     const float* __restrict__ b_att,
                     const float* __restrict__ W1,
                     _Float16* __restrict__ Sp,
                     float* __restrict__ cgout)
{
    const int blk = blockIdx.x;
    const int o = blk / 10, t = blk - o * 10;
    int ti, tj; tileOf(t, ti, tj);
    const int Fi = ti * 32, Ej = tj * 32;
    const float* __restrict__ W1o = W1 + (size_t)o * (KK * DD);

    __shared__ float WaF[KK][32];
    __shared__ float WaE[KK][32];
    __shared__ float W1F[KK][32];
    __shared__ float W1E[KK][32];
    __shared__ float AFE[32][33];
    __shared__ float AEF[32][33];
    __shared__ float bsh[KK];

    const int tid = threadIdx.x;

    for (int r0 = 0; r0 < KK; r0 += 8) {
        const int r = r0 + (tid >> 5), cc = tid & 31;
        WaF[r][cc] = Wa[r * DD + Fi + cc];
        WaE[r][cc] = Wa[r * DD + Ej + cc];
        W1F[r][cc] = W1o[r * DD + Fi + cc];
        W1E[r][cc] = W1o[r * DD + Ej + cc];
    }
    if (tid < KK) bsh[tid] = b_att[tid];
    __syncthreads();

    {
        const int rloc = tid >> 3;
        const int q    = (tid & 7) * 4;
        float a0 = 0.f, a1 = 0.f, a2 = 0.f, a3 = 0.f;
        float b0 = 0.f, b1 = 0.f, b2 = 0.f, b3 = 0.f;
        for (int k = 0; k < KK; ++k) {
            const float av = WaF[k][rloc];
            const float4 wv = *(const float4*)&W1E[k][q];
            a0 += av * wv.x; a1 += av * wv.y; a2 += av * wv.z; a3 += av * wv.w;
            const float bv = WaE[k][rloc];
            const float4 vv = *(const float4*)&W1F[k][q];
            b0 += bv * vv.x; b1 += bv * vv.y; b2 += bv * vv.z; b3 += bv * vv.w;
        }
        AFE[rloc][q] = a0; AFE[rloc][q + 1] = a1; AFE[rloc][q + 2] = a2; AFE[rloc][q + 3] = a3;
        AEF[rloc][q] = b0; AEF[rloc][q + 1] = b1; AEF[rloc][q + 2] = b2; AEF[rloc][q + 3] = b3;
    }
    __syncthreads();

    {
        const int l  = tid & 63;
        const int rq = tid >> 6;
        const int eg = l & 31;
        const int e  = Ej + eg;
        f16x4 p;
#pragma unroll
        for (int j = 0; j < 4; ++j) {
            const int fl = j + 8 * rq + 4 * (l >> 5);
            const int f  = Fi + fl;
            float v;
            if (f < e)       v = AFE[fl][eg] + AEF[eg][fl];
            else if (f == e) v = AFE[fl][eg];
            else             v = 0.f;
            p[j] = (_Float16)v;
        }
        *(f16x4*)&Sp[(size_t)((o * 10 + t) * 64 + l) * 16 + rq * 4] = p;
    }

    if (ti == 0 && tid < 32) {
        float s = 0.f;
        for (int k = 0; k < KK; ++k) s += bsh[k] * W1E[k][tid];
        cgout[o * DD + Ej + tid] = s;
    }
}

// ---------------------------------------------------------------------------
// Kernel 2: one block per TWO graphs, 512 threads = 8 waves, 7 barriers.
// LDS: XtL [0,16K) | GL [16K,48K) de-aliased; PP (40K, ph4/5) aliases union;
//      sp 4 KB, sA/sB 1 KB -> ~54 KB. Schedule:
//   ph0A |B1| (ldB-issue ; ph1A) |B2| (ph2A ; stB->XtL) |B3|
//   (colsumA ; ph3A) |B4| ph1B ; ph2B |B5| (colsumB ; ph3B) |B6| ph4 |B7| ph5
// Extra H-tiles 8,9: graph A on waves 6,7; graph B on waves 4,5 (shared hX1).
// ph4/ph5: R15-verbatim (f16 Sp + dot2). Values bit-identical to R15.
// ---------------------------------------------------------------------------
__global__ __launch_bounds__(512)
void graph_kernel(const float* __restrict__ x,
                  const _Float16* __restrict__ Sp,
                  const float* __restrict__ cg,
                  const float* __restrict__ bias1,
                  float* __restrict__ out)
{
    __shared__ __align__(16) char ldsraw[48 * 1024];      // XtL 16K | GL 32K
    __shared__ float sp[8][DD];                           // 4 KB
    __shared__ float sA[DD], sB[DD];

    __bf16* const XtL = (__bf16*)ldsraw;                  // [0, 16K)
    __bf16* const GL  = (__bf16*)(ldsraw + 16 * 1024);    // [16K, 48K)
    float*  const PP  = (float*)ldsraw;                   // 40K (ph4/5)

    const int g0  = blockIdx.x * 2;
    const int g1  = g0 + 1;
    const int tid = threadIdx.x;
    const int w   = tid >> 6;
    const int l   = tid & 63;
    const int l31 = l & 31;
    const int l5  = l >> 5;
    const int f   = tid & 127, half = tid >> 7;
    const float* __restrict__ xgA = x + (size_t)g0 * NN * DD;
    const float* __restrict__ xgB = x + (size_t)g1 * NN * DD;

    const int ti  = w & 3;
    const int tj0 = (w >> 2) * 2;

    // ---- ph0A: load A's X column-wise, store X^T bf16 ----
    {
#pragma unroll
        for (int ch = 0; ch < 2; ++ch) {
            float v[8];
#pragma unroll
            for (int i = 0; i < 8; ++i) v[i] = xgA[(half * 16 + ch * 8 + i) * DD + f];
            bf16x8 p;
#pragma unroll
            for (int i = 0; i < 8; ++i) p[i] = (__bf16)v[i];
            *(bf16x8*)&XtL[xtIdx(f, half * 16 + ch * 8)] = p;
        }
    }
    __syncthreads();   // B1: XtL(A) ready

    // ---- issue graph B's x loads (latency hides under ph1A + B2) ----
    float vB[16];
#pragma unroll
    for (int i = 0; i < 16; ++i) vB[i] = xgB[(half * 16 + i) * DD + f];

    f32x16 hA0, hB0, hX1;
#pragma unroll
    for (int i = 0; i < 16; ++i) hX1[i] = 0.f;

    // ---- ph1A: gram tiles (ti,tj0), (ti,tj0+1) ----
    f32x16 acc0, acc1;
#pragma unroll
    for (int i = 0; i < 16; ++i) { acc0[i] = 0.f; acc1[i] = 0.f; }
    {
        const int arow  = ti  * 32 + l31;
        const int brow0 = tj0 * 32 + l31;
#pragma unroll
        for (int ks = 0; ks < 4; ++ks) {
            const int kc = ks * 16 + l5 * 8;
            bf16x8 a  = *(const bf16x8*)&XtL[xtIdx(arow, kc)];
            bf16x8 b0 = *(const bf16x8*)&XtL[xtIdx(brow0, kc)];
            bf16x8 b1 = *(const bf16x8*)&XtL[xtIdx(brow0 + 32, kc)];
            acc0 = __builtin_amdgcn_mfma_f32_32x32x16_bf16(a, b0, acc0, 0, 0, 0);
            acc1 = __builtin_amdgcn_mfma_f32_32x32x16_bf16(a, b1, acc1, 0, 0, 0);
        }
    }
    __syncthreads();   // B2: XtL(A) reads done -> XtL free for B

    // ---- ph2A: quantize -> GL + sp partials ; ph0B store (concurrent) ----
    {
        float sum0 = 0.f, sum1 = 0.f;
#pragma unroll
        for (int tt = 0; tt < 2; ++tt) {
            const int e = (tj0 + tt) * 32 + l31;
#pragma unroll
            for (int g2 = 0; g2 < 4; ++g2) {
                bf16x4 p;
#pragma unroll
                for (int j = 0; j < 4; ++j) {
                    const float av = tt ? acc1[g2 * 4 + j] : acc0[g2 * 4 + j];
                    const float q = rintf(av * 100.f) * 0.01f;
                    p[j] = (__bf16)q;
                    if (tt) sum1 += q; else sum0 += q;
                }
                *(bf16x4*)&GL[gIdx(e, ti * 32 + g2 * 8 + l5 * 4)] = p;
            }
        }
        sp[ti * 2 + l5][tj0 * 32 + l31]       = sum0;
        sp[ti * 2 + l5][(tj0 + 1) * 32 + l31] = sum1;
    }
    {
        bf16x8 p0, p1;
#pragma unroll
        for (int i = 0; i < 8; ++i) { p0[i] = (__bf16)vB[i]; p1[i] = (__bf16)vB[8 + i]; }
        *(bf16x8*)&XtL[xtIdx(f, half * 16)]     = p0;
        *(bf16x8*)&XtL[xtIdx(f, half * 16 + 8)] = p1;
    }
    __syncthreads();   // B3: GL(A)+sp ready; XtL(B) stored

    // ---- colsumA (waves 2,3) ; ph3A ----
    if (w == 2 || w == 3) {
        const int e = (w - 2) * 64 + l;
        float s = 0.f;
#pragma unroll
        for (int i = 0; i < 8; ++i) s += sp[i][e];
        sA[e] = s;
    }
#pragma unroll
    for (int i = 0; i < 16; ++i) hA0[i] = 0.f;
    {
        int hti, htj; tileOf(w, hti, htj);
        const int ra = hti * 32 + l31, rb = htj * 32 + l31;
#pragma unroll
        for (int ks = 0; ks < 8; ++ks) {
            const int kc = ks * 16 + l5 * 8;
            bf16x8 a = *(const bf16x8*)&GL[gIdx(ra, kc)];
            bf16x8 b = *(const bf16x8*)&GL[gIdx(rb, kc)];
            hA0 = __builtin_amdgcn_mfma_f32_32x32x16_bf16(a, b, hA0, 0, 0, 0);
        }
    }
    if (w >= 6) {
        int ti1, tj1; tileOf(8 + (w - 6), ti1, tj1);
        const int ra = ti1 * 32 + l31, rb = tj1 * 32 + l31;
#pragma unroll
        for (int ks = 0; ks < 8; ++ks) {
            const int kc = ks * 16 + l5 * 8;
            bf16x8 a = *(const bf16x8*)&GL[gIdx(ra, kc)];
            bf16x8 b = *(const bf16x8*)&GL[gIdx(rb, kc)];
            hX1 = __builtin_amdgcn_mfma_f32_32x32x16_bf16(a, b, hX1, 0, 0, 0);
        }
    }
    __syncthreads();   // B4: GL(A) reads done; XtL(B) ready; sA visible

    // ---- ph1B (XtL) ; ph2B (GL de-aliased: no barrier between) ----
#pragma unroll
    for (int i = 0; i < 16; ++i) { acc0[i] = 0.f; acc1[i] = 0.f; }
    {
        const int arow  = ti  * 32 + l31;
        const int brow0 = tj0 * 32 + l31;
#pragma unroll
        for (int ks = 0; ks < 4; ++ks) {
            const int kc = ks * 16 + l5 * 8;
            bf16x8 a  = *(const bf16x8*)&XtL[xtIdx(arow, kc)];
            bf16x8 b0 = *(const bf16x8*)&XtL[xtIdx(brow0, kc)];
            bf16x8 b1 = *(const bf16x8*)&XtL[xtIdx(brow0 + 32, kc)];
            acc0 = __builtin_amdgcn_mfma_f32_32x32x16_bf16(a, b0, acc0, 0, 0, 0);
            acc1 = __builtin_amdgcn_mfma_f32_32x32x16_bf16(a, b1, acc1, 0, 0, 0);
        }
    }
    {
        float sum0 = 0.f, sum1 = 0.f;
#pragma unroll
        for (int tt = 0; tt < 2; ++tt) {
            const int e = (tj0 + tt) * 32 + l31;
#pragma unroll
            for (int g2 = 0; g2 < 4; ++g2) {
                bf16x4 p;
#pragma unroll
                for (int j = 0; j < 4; ++j) {
                    const float av = tt ? acc1[g2 * 4 + j] : acc0[g2 * 4 + j];
                    const float q = rintf(av * 100.f) * 0.01f;
                    p[j] = (__bf16)q;
                    if (tt) sum1 += q; else sum0 += q;
                }
                *(bf16x4*)&GL[gIdx(e, ti * 32 + g2 * 8 + l5 * 4)] = p;
            }
        }
        sp[ti * 2 + l5][tj0 * 32 + l31]       = sum0;
        sp[ti * 2 + l5][(tj0 + 1) * 32 + l31] = sum1;
    }
    __syncthreads();   // B5: GL(B)+sp ready

    // ---- colsumB (waves 2,3) ; ph3B ----
    if (w == 2 || w == 3) {
        const int e = (w - 2) * 64 + l;
        float s = 0.f;
#pragma unroll
        for (int i = 0; i < 8; ++i) s += sp[i][e];
        sB[e] = s;
    }
#pragma unroll
    for (int i = 0; i < 16; ++i) hB0[i] = 0.f;
    {
        int hti, htj; tileOf(w, hti, htj);
        const int ra = hti * 32 + l31, rb = htj * 32 + l31;
#pragma unroll
        for (int ks = 0; ks < 8; ++ks) {
            const int kc = ks * 16 + l5 * 8;
            bf16x8 a = *(const bf16x8*)&GL[gIdx(ra, kc)];
            bf16x8 b = *(const bf16x8*)&GL[gIdx(rb, kc)];
            hB0 = __builtin_amdgcn_mfma_f32_32x32x16_bf16(a, b, hB0, 0, 0, 0);
        }
    }
    if (w == 4 || w == 5) {
        int ti1, tj1; tileOf(8 + (w - 4), ti1, tj1);
        const int ra = ti1 * 32 + l31, rb = tj1 * 32 + l31;
#pragma unroll
        for (int ks = 0; ks < 8; ++ks) {
            const int kc = ks * 16 + l5 * 8;
            bf16x8 a = *(const bf16x8*)&GL[gIdx(ra, kc)];
            bf16x8 b = *(const bf16x8*)&GL[gIdx(rb, kc)];
            hX1 = __builtin_amdgcn_mfma_f32_32x32x16_bf16(a, b, hX1, 0, 0, 0);
        }
    }
    __syncthreads();   // B6: GL(B) reads done -> PP region free; sB visible

    // ---- convert H accumulators to packed half2 (AGPRs die here) ----
    h16x2 hA[8], hB[8], hX[8];
#pragma unroll
    for (int i = 0; i < 8; ++i) {
        hA[i] = __builtin_amdgcn_cvt_pkrtz(hA0[2 * i], hA0[2 * i + 1]);
        hB[i] = __builtin_amdgcn_cvt_pkrtz(hB0[2 * i], hB0[2 * i + 1]);
        hX[i] = __builtin_amdgcn_cvt_pkrtz(hX1[2 * i], hX1[2 * i + 1]);
    }

    // ---- phase 4 (R15 verbatim): contraction with Sp ----
#pragma unroll
    for (int o = 0; o < OUTD; ++o) {
        const _Float16* __restrict__ spp = Sp + (size_t)((o * 10 + w) * 64 + l) * 16;
        const h16x8 s0 = *(const h16x8*)&spp[0];
        const h16x8 s1 = *(const h16x8*)&spp[8];
        float tA = 0.f, tB = 0.f;
#pragma unroll
        for (int i = 0; i < 4; ++i) {
            const h16x2 p = { s0[2 * i], s0[2 * i + 1] };
            tA = dot2f(p, hA[i], tA);
            tB = dot2f(p, hB[i], tB);
        }
#pragma unroll
        for (int i = 0; i < 4; ++i) {
            const h16x2 p = { s1[2 * i], s1[2 * i + 1] };
            tA = dot2f(p, hA[4 + i], tA);
            tB = dot2f(p, hB[4 + i], tB);
        }
        if (w >= 4) {
            const _Float16* __restrict__ sp2 =
                Sp + (size_t)((o * 10 + 8 + (w & 1)) * 64 + l) * 16;
            const h16x8 e0 = *(const h16x8*)&sp2[0];
            const h16x8 e1 = *(const h16x8*)&sp2[8];
            float tx = 0.f;
#pragma unroll
            for (int i = 0; i < 4; ++i) {
                const h16x2 p = { e0[2 * i], e0[2 * i + 1] };
                tx = dot2f(p, hX[i], tx);
            }
#pragma unroll
            for (int i = 0; i < 4; ++i) {
                const h16x2 p = { e1[2 * i], e1[2 * i + 1] };
                tx = dot2f(p, hX[4 + i], tx);
            }
            if (w >= 6) tA += tx; else tB += tx;
        }
        if (w == 0) {
            tA += cg[o * DD + l] * sA[l] + cg[o * DD + 64 + l] * sA[64 + l];
            tB += cg[o * DD + l] * sB[l] + cg[o * DD + 64 + l] * sB[64 + l];
        }
        PP[o * 512 + tid]        = tA;
        PP[(10 + o) * 512 + tid] = tB;
    }
    __syncthreads();   // B7: PP ready

    // ---- phase 5: 20 reduce instances over 8 waves ----
    for (int p = w; p < 2 * OUTD; p += 8) {
        const float4 q0 = *(const float4*)&PP[p * 512 + l * 8];
        const float4 q1 = *(const float4*)&PP[p * 512 + l * 8 + 4];
        float v = (q0.x + q0.y) + (q0.z + q0.w) + (q1.x + q1.y) + (q1.z + q1.w);
        v += __shfl_down(v, 32, 64);
        v += __shfl_down(v, 16, 64);
        v += __shfl_down(v, 8, 64);
        v += __shfl_down(v, 4, 64);
        v += __shfl_down(v, 2, 64);
        v += __shfl_down(v, 1, 64);
        if (l == 0) {
            const int gg = (p < OUTD) ? g0 : g1;
            const int oo = (p < OUTD) ? p : p - OUTD;
            out[(size_t)gg * OUTD + oo] = v + bias1[oo];
        }
    }
}

// ---------------------------------------------------------------------------
extern "C" void kernel_launch(void* const* d_in, const int* in_sizes, int n_in,
                              void* d_out, int out_size, void* d_ws, size_t ws_size,
                              hipStream_t stream)
{
    const float* x     = (const float*)d_in[0];
    const float* Wa    = (const float*)d_in[1];
    const float* b_att = (const float*)d_in[2];
    const float* W1    = (const float*)d_in[3];
    const float* bias1 = (const float*)d_in[4];
    float* out = (float*)d_out;

    float*    cg = (float*)d_ws;                     // 1280 f32 (5 KB)
    _Float16* Sp = (_Float16*)(cg + OUTD * DD);      // 102400 f16 (200 KB)

    fused_sp_kernel<<<100, 256, 0, stream>>>(Wa, b_att, W1, Sp, cg);
    graph_kernel<<<NG / 2, 512, 0, stream>>>(x, Sp, cg, bias1, out);
}